// Round 2
// baseline (2167.753 us; speedup 1.0000x reference)
//
#include <hip/hip_runtime.h>
#include <stdint.h>

// ===================== Round 2 =====================
// Plain-HIP-only data path (no tr_b16, no inline asm): staging is [m][k]
// row-major fp16 (+8 short pad), scalar b16 writes, b128 A-frag reads.
// M=32/wave (2 m-tiles per B-frag), 8 waves/block, 256 rows/block.
// Predict: PASS, absmax 0.01-0.06, 700-1000us, MfmaUtil 45-65%.
// ===================================================

typedef _Float16 half8 __attribute__((ext_vector_type(8)));
typedef float f32x4 __attribute__((ext_vector_type(4)));
typedef __attribute__((address_space(3))) char lchar;
typedef __attribute__((address_space(1))) char gchar;

#define KSTR 136  // shorts per staging row: 128 + 8 pad (16B) -> 272B rows

static __device__ __forceinline__ void gload_lds16(const void* g, void* l) {
  __builtin_amdgcn_global_load_lds((const gchar*)g, (lchar*)l, 16, 0, 0);
}

static __device__ __forceinline__ unsigned short f2h(float x) {
  union { _Float16 h; unsigned short u; } cv;
  cv.h = (_Float16)x;
  return cv.u;
}

// Prepack W1 (128x512) and W2 (512x128) fp32 -> fp16 MFMA B-frag streams.
// B-frag layout (16x16x32): lane l holds B[k][n], n = l&15, k = (l>>4)*8 + j.
// W1 frag id = c*16 + nt*4 + ks  (c: 8 chunks of 64 cols, nt: 4, ks: 4)
// W2 frag id = c*16 + nt*2 + ks  (c: 8 chunks of 64 k-rows, nt: 8, ks: 2)
__global__ void pack_w(const float* __restrict__ W1, const float* __restrict__ W2,
                       unsigned short* __restrict__ w1p, unsigned short* __restrict__ w2p) {
  int id = blockIdx.x * 256 + threadIdx.x;  // 0..16383
  int lane = id & 63, fid = (id >> 6) & 127;
  int g = lane >> 4, lm = lane & 15;
  if (id < 8192) {
    int c = fid >> 4, nt = (fid >> 2) & 3, ks = fid & 3;
    int n = c * 64 + nt * 16 + lm;
#pragma unroll
    for (int j = 0; j < 8; ++j) {
      int k = ks * 32 + g * 8 + j;
      w1p[fid * 512 + lane * 8 + j] = f2h(W1[k * 512 + n]);
    }
  } else {
    int c = fid >> 4, nt = (fid >> 1) & 7, ks = fid & 1;
    int u = nt * 16 + lm;
#pragma unroll
    for (int j = 0; j < 8; ++j) {
      int k = c * 64 + ks * 32 + g * 8 + j;
      w2p[fid * 512 + lane * 8 + j] = f2h(W2[k * 128 + u]);
    }
  }
}

__global__ __launch_bounds__(512, 2) void node_rk4(
    const float* __restrict__ x0, const float* __restrict__ b1,
    const float* __restrict__ b2, const unsigned short* __restrict__ w1p,
    const unsigned short* __restrict__ w2p, float* __restrict__ out) {
  // LDS: W double-buffer 64KB + per-wave staging 8*32*136*2 = 68KB + biases.
  __shared__ char Wbuf[2][32768];
  __shared__ unsigned short stg[8][32][KSTR];
  __shared__ float b1s[512];
  __shared__ float b2s[128];

  const int tid = threadIdx.x;
  const int w = tid >> 6, lane = tid & 63;
  const int g = lane >> 4, lm = lane & 15;
  unsigned short(*stage)[KSTR] = stg[w];

  b1s[tid] = b1[tid];  // blockDim == 512
  if (tid < 128) b2s[tid] = b2[tid];

  // State in GEMM2 C/D layout: element (row rbase + mt*16 + g*4 + j,
  // col t*16 + lm) lives in xb[mt][t][j] (fp32).
  const int rbase = blockIdx.x * 256 + w * 32;
  f32x4 xb[2][8], xa[2][8];
#pragma unroll
  for (int mt = 0; mt < 2; ++mt)
#pragma unroll
    for (int t = 0; t < 8; ++t) {
#pragma unroll
      for (int j = 0; j < 4; ++j)
        xb[mt][t][j] = x0[(rbase + mt * 16 + g * 4 + j) * 128 + t * 16 + lm];
      xa[mt][t] = xb[mt][t];
#pragma unroll
      for (int j = 0; j < 4; ++j)
        stage[mt * 16 + g * 4 + j][t * 16 + lm] = f2h(xb[mt][t][j]);
    }

  // Prologue: stage W chunk 0 into Wbuf[0] (32 KB: 16KB W1-frags + 16KB W2-frags)
  {
    const char* s1 = (const char*)w1p;
    const char* s2 = (const char*)w2p;
#pragma unroll
    for (int q = 0; q < 2; ++q) {
      int seg = w * 2 + q;
      gload_lds16(s1 + seg * 1024 + lane * 16, Wbuf[0] + seg * 1024);
      gload_lds16(s2 + seg * 1024 + lane * 16, Wbuf[0] + 16384 + seg * 1024);
    }
  }
  __syncthreads();  // Wbuf[0] landed (vmcnt drained), b1s/b2s visible

#pragma unroll 1
  for (int it = 0; it < 80; ++it) {
    const int s = it & 3;
    const float wgt = (s == 0 || s == 3) ? (0.1f / 6.0f) : (0.1f / 3.0f);
    const float alph = (s < 2) ? 0.05f : 0.1f;

    // x_in A-frags for the whole eval (K=128): lane needs
    // A[m = lm][k = ks*32 + g*8 .. +7] -> one b128 per (mt,ks).
    half8 A1[2][4];
#pragma unroll
    for (int mt = 0; mt < 2; ++mt)
#pragma unroll
      for (int ks = 0; ks < 4; ++ks)
        A1[mt][ks] = *(const half8*)&stage[mt * 16 + lm][ks * 32 + g * 8];

    f32x4 yacc[2][8];
#pragma unroll
    for (int mt = 0; mt < 2; ++mt)
#pragma unroll
      for (int t = 0; t < 8; ++t) yacc[mt][t] = f32x4{0.f, 0.f, 0.f, 0.f};

#pragma unroll
    for (int c = 0; c < 8; ++c) {
      // Prefetch next W chunk into the other buffer. Safe: the barrier ending
      // chunk c-1 means no wave still reads that buffer; the barrier ending
      // chunk c drains vmcnt before anyone reads it.
      {
        const int cn = (c + 1) & 7;
        char* buf = Wbuf[(c + 1) & 1];
        const char* s1 = (const char*)w1p + cn * 16384;
        const char* s2 = (const char*)w2p + cn * 16384;
#pragma unroll
        for (int q = 0; q < 2; ++q) {
          int seg = w * 2 + q;
          gload_lds16(s1 + seg * 1024 + lane * 16, buf + seg * 1024);
          gload_lds16(s2 + seg * 1024 + lane * 16, buf + 16384 + seg * 1024);
        }
      }
      const char* Wb = Wbuf[c & 1];

      // GEMM1: h[32 x 64] = x_in(32x128) @ W1[:, c*64 .. +64)
      // Each B-frag feeds both m-tiles. h -> relu -> fp16 -> stage cols 0..63.
#pragma unroll
      for (int nt = 0; nt < 4; ++nt) {
        f32x4 h0 = {0.f, 0.f, 0.f, 0.f}, h1 = {0.f, 0.f, 0.f, 0.f};
#pragma unroll
        for (int ks = 0; ks < 4; ++ks) {
          half8 bf = *(const half8*)(Wb + (nt * 4 + ks) * 1024 + lane * 16);
          h0 = __builtin_amdgcn_mfma_f32_16x16x32_f16(A1[0][ks], bf, h0, 0, 0, 0);
          h1 = __builtin_amdgcn_mfma_f32_16x16x32_f16(A1[1][ks], bf, h1, 0, 0, 0);
        }
        float bb = b1s[c * 64 + nt * 16 + lm];
#pragma unroll
        for (int j = 0; j < 4; ++j) {
          stage[g * 4 + j][nt * 16 + lm] = f2h(fmaxf(h0[j] + bb, 0.f));
          stage[16 + g * 4 + j][nt * 16 + lm] = f2h(fmaxf(h1[j] + bb, 0.f));
        }
      }

      // h A-frags (chunk-local K=64)
      half8 A2[2][2];
#pragma unroll
      for (int mt = 0; mt < 2; ++mt)
#pragma unroll
        for (int k2 = 0; k2 < 2; ++k2)
          A2[mt][k2] = *(const half8*)&stage[mt * 16 + lm][k2 * 32 + g * 8];

      // GEMM2 partial: y(32x128) += h(32x64) @ W2[c*64 .. +64, :)
#pragma unroll
      for (int nt = 0; nt < 8; ++nt)
#pragma unroll
        for (int k2 = 0; k2 < 2; ++k2) {
          half8 bf = *(const half8*)(Wb + 16384 + (nt * 2 + k2) * 1024 + lane * 16);
          yacc[0][nt] =
              __builtin_amdgcn_mfma_f32_16x16x32_f16(A2[0][k2], bf, yacc[0][nt], 0, 0, 0);
          yacc[1][nt] =
              __builtin_amdgcn_mfma_f32_16x16x32_f16(A2[1][k2], bf, yacc[1][nt], 0, 0, 0);
        }
      __syncthreads();  // drains prefetch vmcnt; protects W buffers
    }

    // RK4 combine; write next x_in (fp16) into staging.
#pragma unroll
    for (int mt = 0; mt < 2; ++mt)
#pragma unroll
      for (int t = 0; t < 8; ++t) {
        f32x4 k = yacc[mt][t];
        float bb = b2s[t * 16 + lm];
#pragma unroll
        for (int j = 0; j < 4; ++j) k[j] += bb;
        xa[mt][t] += wgt * k;
        f32x4 xi;
        if (s == 3) {
          xb[mt][t] = xa[mt][t];
          xi = xa[mt][t];
        } else {
          xi = xb[mt][t] + alph * k;
        }
#pragma unroll
        for (int j = 0; j < 4; ++j)
          stage[mt * 16 + g * 4 + j][t * 16 + lm] = f2h(xi[j]);
      }
  }

#pragma unroll
  for (int mt = 0; mt < 2; ++mt)
#pragma unroll
    for (int t = 0; t < 8; ++t)
#pragma unroll
      for (int j = 0; j < 4; ++j)
        out[(rbase + mt * 16 + g * 4 + j) * 128 + t * 16 + lm] = xb[mt][t][j];
}

extern "C" void kernel_launch(void* const* d_in, const int* in_sizes, int n_in,
                              void* d_out, int out_size, void* d_ws, size_t ws_size,
                              hipStream_t stream) {
  const float* x0 = (const float*)d_in[0];
  const float* W1 = (const float*)d_in[1];
  const float* b1 = (const float*)d_in[2];
  const float* W2 = (const float*)d_in[3];
  const float* b2 = (const float*)d_in[4];
  float* out = (float*)d_out;

  unsigned short* w1p = (unsigned short*)d_ws;  // 128 frags * 1KB = 128KB
  unsigned short* w2p = w1p + 65536;            // next 128KB

  pack_w<<<64, 256, 0, stream>>>(W1, W2, w1p, w2p);
  node_rk4<<<256, 512, 0, stream>>>(x0, b1, b2, w1p, w2p, out);
}